// Round 8
// baseline (87.937 us; speedup 1.0000x reference)
//
#include <hip/hip_runtime.h>
#include <hip/hip_bf16.h>
#include <math.h>

#define BB 2
#define NN 2048
#define DD 256
#define HH 8

typedef __attribute__((ext_vector_type(8))) short bfrag8;
typedef __attribute__((ext_vector_type(4))) short bfrag4;
typedef __attribute__((ext_vector_type(4))) float f32x4;
typedef __attribute__((ext_vector_type(4))) unsigned short us4;
typedef __attribute__((ext_vector_type(8))) short s8v;

__device__ __forceinline__ unsigned short bf16rn(float f) {
    union { float f; unsigned u; } un; un.f = f;
    unsigned r = un.u + 0x7FFFu + ((un.u >> 16) & 1u);
    return (unsigned short)(r >> 16);
}

__device__ __forceinline__ f32x4 mfma16(bfrag4 a, bfrag4 b, f32x4 c) {
#if __has_builtin(__builtin_amdgcn_mfma_f32_16x16x16_bf16)
    return __builtin_amdgcn_mfma_f32_16x16x16_bf16(a, b, c, 0, 0, 0);
#else
    return __builtin_amdgcn_mfma_f32_16x16x16bf16_1k(a, b, c, 0, 0, 0);
#endif
}

// pair swizzle for the imag dot: {q0,q1,...} -> {q1,-q0,q3,-q2,...}
__device__ __forceinline__ bfrag8 pairswz(bfrag8 q) {
    union { bfrag8 f; unsigned u[4]; } a, r;
    a.f = q;
#pragma unroll
    for (int i = 0; i < 4; ++i) {
        unsigned d = a.u[i];
        r.u[i] = ((d >> 16) | (d << 16)) ^ 0x80000000u;
    }
    return r.f;
}

// w-chain: y = SC2 * re/|z|;  P = exp(y) via cubic Taylor (|y|<=0.0884);
// pack 4 probs to bf16 pairs with v_cvt_pk_bf16_f32.   (r3/r6-verified)
__device__ __forceinline__ bfrag4 expchain(f32x4 re, f32x4 im, float SC2) {
    float p[4];
#pragma unroll
    for (int r = 0; r < 4; ++r) {
        const float rr = re[r], ii = im[r];
        const float r2 = fmaf(rr, rr, fmaf(ii, ii, 1e-30f));
        const float y  = SC2 * rr * __builtin_amdgcn_rsqf(r2);
        const float a  = fmaf(y, 0.16666667f, 0.5f);
        const float bq = fmaf(y, a, 1.0f);
        p[r] = fmaf(y, bq, 1.0f);
    }
    unsigned lo, hi;
    asm("v_cvt_pk_bf16_f32 %0, %1, %2" : "=v"(lo) : "v"(p[0]), "v"(p[1]));
    asm("v_cvt_pk_bf16_f32 %0, %1, %2" : "=v"(hi) : "v"(p[2]), "v"(p[3]));
    union { unsigned u[2]; bfrag4 f; } pu;
    pu.u[0] = lo; pu.u[1] = hi;
    return pu.f;
}

// ---------------------------------------------------------------------------
// K0: convert X and Wq/Wk/Wv f32 -> bf16.  (r6-verified, unchanged)
// ---------------------------------------------------------------------------
__global__ __launch_bounds__(256) void cvt_inputs(
    const float* __restrict__ X,
    const float* __restrict__ Wq, const float* __restrict__ Wk, const float* __restrict__ Wv,
    unsigned short* __restrict__ Xb,
    unsigned short* __restrict__ Wqb, unsigned short* __restrict__ Wkb, unsigned short* __restrict__ Wvb)
{
    const int i = blockIdx.x * 256 + threadIdx.x;
    const float* src; unsigned short* dst; size_t off;
    if (i < 131072)      { src = X;  dst = Xb;  off = (size_t)i * 8; }
    else if (i < 139264) { src = Wq; dst = Wqb; off = (size_t)(i - 131072) * 8; }
    else if (i < 147456) { src = Wk; dst = Wkb; off = (size_t)(i - 139264) * 8; }
    else                 { src = Wv; dst = Wvb; off = (size_t)(i - 147456) * 8; }
    float4 a = *(const float4*)(src + off);
    float4 b = *(const float4*)(src + off + 4);
    us4 lo = { bf16rn(a.x), bf16rn(a.y), bf16rn(a.z), bf16rn(a.w) };
    us4 hi = { bf16rn(b.x), bf16rn(b.y), bf16rn(b.z), bf16rn(b.w) };
    *(us4*)(dst + off)     = lo;
    *(us4*)(dst + off + 4) = hi;
}

// ---------------------------------------------------------------------------
// K1: MFMA QKV GEMM (64x64 tile, XOR-swizzled LDS).  (r6-verified, unchanged)
// ---------------------------------------------------------------------------
__global__ __launch_bounds__(256) void qkv_mfma(
    const unsigned short* __restrict__ Xb,
    const unsigned short* __restrict__ Wqb, const unsigned short* __restrict__ Wkb,
    const unsigned short* __restrict__ Wvb,
    const float* __restrict__ bq, const float* __restrict__ bk, const float* __restrict__ bv,
    unsigned short* __restrict__ Qb, unsigned short* __restrict__ Kb, unsigned short* __restrict__ Vb)
{
    const int tid  = threadIdx.x;
    const int z    = blockIdx.z;
    const unsigned short* Wm = (z == 0) ? Wqb : (z == 1) ? Wkb : Wvb;
    const float*          bm = (z == 0) ? bq  : (z == 1) ? bk  : bv;

    const int Mbase = blockIdx.x * 64;
    const int Nbase = blockIdx.y * 64;

    __shared__ unsigned short Xs[64 * 64];
    __shared__ unsigned short Ws[64 * 64];

    const int wave = tid >> 6, lane = tid & 63;
    const int c = lane & 15, g = lane >> 4;

    const int srow = tid >> 2;
    const int sq   = tid & 3;
    const int soff = ((srow * 128 + sq * 16) ^ ((srow & 7) << 4));
    const unsigned short* gx = Xb + (size_t)(Mbase + srow) * DD + sq * 8;
    const unsigned short* gw = Wm + (size_t)(Nbase + srow) * DD + sq * 8;

    const int xrow = 16 * wave + c;
    const int xoff = ((xrow * 128 + g * 16) ^ ((xrow & 7) << 4));
    int woff[4];
#pragma unroll
    for (int j = 0; j < 4; ++j) {
        const int wrow = 16 * j + c;
        woff[j] = ((wrow * 128 + g * 16) ^ ((wrow & 7) << 4));
    }

    f32x4 acc[4];
#pragma unroll
    for (int j = 0; j < 4; ++j) acc[j] = (f32x4){0.f, 0.f, 0.f, 0.f};

    for (int k0 = 0; k0 < DD; k0 += 32) {
        *(s8v*)((char*)Xs + soff) = *(const s8v*)(gx + k0);
        *(s8v*)((char*)Ws + soff) = *(const s8v*)(gw + k0);
        __syncthreads();
        const bfrag8 xf = *(const bfrag8*)((const char*)Xs + xoff);
#pragma unroll
        for (int j = 0; j < 4; ++j) {
            const bfrag8 wf = *(const bfrag8*)((const char*)Ws + woff[j]);
            acc[j] = __builtin_amdgcn_mfma_f32_16x16x32_bf16(wf, xf, acc[j], 0, 0, 0);
        }
        __syncthreads();
    }

    const int n = Mbase + xrow;
    const int bb = n >> 11, m = n & (NN - 1);
#pragma unroll
    for (int j = 0; j < 4; ++j) {
        const int col0 = Nbase + 16 * j + 4 * g;
        float4 bias = *(const float4*)(bm + col0);
        float v0 = acc[j][0] + bias.x;
        float v1 = acc[j][1] + bias.y;
        float v2 = acc[j][2] + bias.z;
        float v3 = acc[j][3] + bias.w;
        if (z == 2) {
            const int t = m >> 4, gg = (m >> 2) & 3, jj = m & 3;
            const int h2 = col0 >> 5, dt = (col0 >> 4) & 1, cc0 = col0 & 15;
            const size_t base = (size_t)(bb * 8 + h2) * 65536
                              + (size_t)t * 512 + (size_t)(dt * 4 + jj);
            Vb[base + (size_t)(16 * gg + cc0 + 0) * 8] = bf16rn(v0);
            Vb[base + (size_t)(16 * gg + cc0 + 1) * 8] = bf16rn(v1);
            Vb[base + (size_t)(16 * gg + cc0 + 2) * 8] = bf16rn(v2);
            Vb[base + (size_t)(16 * gg + cc0 + 3) * 8] = bf16rn(v3);
        } else {
            us4 pk = { bf16rn(v0), bf16rn(v1), bf16rn(v2), bf16rn(v3) };
            unsigned short* Ob = (z == 0) ? Qb : Kb;
            *(us4*)(Ob + (size_t)n * DD + col0) = pk;
        }
    }
}

// ---------------------------------------------------------------------------
// K2a: DIAGNOSTIC VARIANT — 8 waves/block (512 thr), 256 keys/wave, 16 iters.
// Writes to ws scratch only; real output produced by K2b below.  Tests the
// grid-limited-TLP theory (current config caps at 16 waves/CU = 50% occ).
// ---------------------------------------------------------------------------
__global__ __launch_bounds__(512) void attn_mfma8(
    const unsigned short* __restrict__ Qb, const unsigned short* __restrict__ Kb,
    const unsigned short* __restrict__ Vb, float* __restrict__ outp)
{
    const int tid  = threadIdx.x;
    const int wave = tid >> 6, lane = tid & 63;
    const int g = lane >> 4, c = lane & 15;
    const int bid  = blockIdx.x;                    // 1024 = 8 * 128
    const int wgid = (bid & 7) * 128 + (bid >> 3);  // bijective XCD cluster
    const int bh = wgid >> 6, qt = wgid & 63;
    const int b = bh >> 3, h = bh & 7;

    const size_t qoff = (size_t)(b * NN + qt * 32 + c) * DD + h * 32 + 8 * g;
    const bfrag8 qf0  = *(const bfrag8*)(Qb + qoff);
    const bfrag8 qf1  = *(const bfrag8*)(Qb + qoff + 16 * DD);
    const bfrag8 qpf0 = pairswz(qf0);
    const bfrag8 qpf1 = pairswz(qf1);

    const unsigned short* kbase = Kb + (size_t)(b * NN + wave * 256 + c) * DD + h * 32 + 8 * g;
    const unsigned short* vbase = Vb + (size_t)bh * 65536 + (size_t)(wave * 16) * 512 + lane * 8;

    const f32x4 zero = {0.f, 0.f, 0.f, 0.f};
    f32x4 o00 = zero, o01 = zero, od0 = zero;
    f32x4 o10 = zero, o11 = zero, od1 = zero;
    const bfrag4 ones = { 0x3F80, 0x3F80, 0x3F80, 0x3F80 };
    const float SC2 = 0.5f / (sqrtf(32.0f) + 1e-6f);

    bfrag8 kf_n = *(const bfrag8*)(kbase + (size_t)16 * DD);
    bfrag8 vf_c = *(const bfrag8*)vbase;
    bfrag8 vf_n = *(const bfrag8*)(vbase + 512);
    {
        const bfrag8 kf_c = *(const bfrag8*)kbase;
        f32x4 t;
        t = __builtin_amdgcn_mfma_f32_16x16x32_bf16(kf_c, qf0,  zero, 0, 0, 0);
        o00 = t;  // reuse o00..o11 as reA/imA holders? no — keep separate:
        o00 = zero;
        (void)t;
    }
    // prologue re/im for tile 0
    f32x4 reA0, imA0, reA1, imA1;
    {
        const bfrag8 kf_c = *(const bfrag8*)kbase;
        reA0 = __builtin_amdgcn_mfma_f32_16x16x32_bf16(kf_c, qf0,  zero, 0, 0, 0);
        imA0 = __builtin_amdgcn_mfma_f32_16x16x32_bf16(kf_c, qpf0, zero, 0, 0, 0);
        reA1 = __builtin_amdgcn_mfma_f32_16x16x32_bf16(kf_c, qf1,  zero, 0, 0, 0);
        imA1 = __builtin_amdgcn_mfma_f32_16x16x32_bf16(kf_c, qpf1, zero, 0, 0, 0);
    }

#pragma unroll 2
    for (int tt = 0; tt < 16; ++tt) {
        const bfrag8 kf_2 = *(const bfrag8*)(kbase + (size_t)(tt + 2) * 16 * DD);
        const bfrag8 vf_2 = *(const bfrag8*)(vbase + (size_t)(tt + 2) * 512);

        const f32x4 reB0 = __builtin_amdgcn_mfma_f32_16x16x32_bf16(kf_n, qf0,  zero, 0, 0, 0);
        const f32x4 imB0 = __builtin_amdgcn_mfma_f32_16x16x32_bf16(kf_n, qpf0, zero, 0, 0, 0);
        const f32x4 reB1 = __builtin_amdgcn_mfma_f32_16x16x32_bf16(kf_n, qf1,  zero, 0, 0, 0);
        const f32x4 imB1 = __builtin_amdgcn_mfma_f32_16x16x32_bf16(kf_n, qpf1, zero, 0, 0, 0);

        const bfrag4 pf0 = expchain(reA0, imA0, SC2);
        const bfrag4 pf1 = expchain(reA1, imA1, SC2);

        union { bfrag8 v8; bfrag4 v4[2]; } vs; vs.v8 = vf_c;
        o00 = mfma16(pf0, vs.v4[0], o00);
        o01 = mfma16(pf0, vs.v4[1], o01);
        od0 = mfma16(pf0, ones,     od0);
        o10 = mfma16(pf1, vs.v4[0], o10);
        o11 = mfma16(pf1, vs.v4[1], o11);
        od1 = mfma16(pf1, ones,     od1);

        reA0 = reB0; imA0 = imB0; reA1 = reB1; imA1 = imB1;
        kf_n = kf_2; vf_c = vf_n; vf_n = vf_2;
    }

    __shared__ float cO[8][32][33];
    __shared__ float cD[8][32];
#pragma unroll
    for (int r = 0; r < 4; ++r) {
        cO[wave][4 * g + r][c]           = o00[r];
        cO[wave][4 * g + r][16 + c]      = o01[r];
        cO[wave][16 + 4 * g + r][c]      = o10[r];
        cO[wave][16 + 4 * g + r][16 + c] = o11[r];
    }
    if (c == 0) {
#pragma unroll
        for (int r = 0; r < 4; ++r) {
            cD[wave][4 * g + r]      = od0[r];
            cD[wave][16 + 4 * g + r] = od1[r];
        }
    }
    __syncthreads();

    const int q  = tid >> 4;   // 0..31
    const int dp = tid & 15;   // cols 2dp, 2dp+1
    float den = 0.f, s0 = 0.f, s1 = 0.f;
#pragma unroll
    for (int w = 0; w < 8; ++w) {
        den += cD[w][q];
        s0  += cO[w][q][2 * dp];
        s1  += cO[w][q][2 * dp + 1];
    }
    const float rden = 1.0f / den;
    float2 ov = make_float2(s0 * rden, s1 * rden);
    *(float2*)(outp + (size_t)(b * NN + qt * 32 + q) * DD + h * 32 + 2 * dp) = ov;
}

// ---------------------------------------------------------------------------
// K2b: MFMA phase attention, r7-verified, UNCHANGED — produces the real output.
// ---------------------------------------------------------------------------
__global__ __launch_bounds__(256, 4) void attn_mfma(
    const unsigned short* __restrict__ Qb, const unsigned short* __restrict__ Kb,
    const unsigned short* __restrict__ Vb, float* __restrict__ outp)
{
    const int tid  = threadIdx.x;
    const int wave = tid >> 6, lane = tid & 63;
    const int g = lane >> 4, c = lane & 15;
    const int bid  = blockIdx.x;                    // 1024 = 8 * 128
    const int wgid = (bid & 7) * 128 + (bid >> 3);  // bijective XCD cluster
    const int bh = wgid >> 6, qt = wgid & 63;
    const int b = bh >> 3, h = bh & 7;

    const size_t qoff = (size_t)(b * NN + qt * 32 + c) * DD + h * 32 + 8 * g;
    const bfrag8 qf0  = *(const bfrag8*)(Qb + qoff);
    const bfrag8 qf1  = *(const bfrag8*)(Qb + qoff + 16 * DD);
    const bfrag8 qpf0 = pairswz(qf0);
    const bfrag8 qpf1 = pairswz(qf1);

    const unsigned short* kbase = Kb + (size_t)(b * NN + wave * 512 + c) * DD + h * 32 + 8 * g;
    const unsigned short* vbase = Vb + (size_t)bh * 65536 + (size_t)(wave * 32) * 512 + lane * 8;

    const f32x4 zero = {0.f, 0.f, 0.f, 0.f};
    f32x4 o00 = zero, o01 = zero, od0 = zero;
    f32x4 o10 = zero, o11 = zero, od1 = zero;
    const bfrag4 ones = { 0x3F80, 0x3F80, 0x3F80, 0x3F80 };
    const float SC2 = 0.5f / (sqrtf(32.0f) + 1e-6f);

    bfrag8 kf_c = *(const bfrag8*)kbase;
    bfrag8 vf_c = *(const bfrag8*)vbase;
    bfrag8 kf_n = *(const bfrag8*)(kbase + (size_t)16 * DD);
    bfrag8 vf_n = *(const bfrag8*)(vbase + 512);

    f32x4 reA0 = __builtin_amdgcn_mfma_f32_16x16x32_bf16(kf_c, qf0,  zero, 0, 0, 0);
    f32x4 imA0 = __builtin_amdgcn_mfma_f32_16x16x32_bf16(kf_c, qpf0, zero, 0, 0, 0);
    f32x4 reA1 = __builtin_amdgcn_mfma_f32_16x16x32_bf16(kf_c, qf1,  zero, 0, 0, 0);
    f32x4 imA1 = __builtin_amdgcn_mfma_f32_16x16x32_bf16(kf_c, qpf1, zero, 0, 0, 0);

#pragma unroll 2
    for (int tt = 0; tt < 32; ++tt) {
        const bfrag8 kf_2 = *(const bfrag8*)(kbase + (size_t)(tt + 2) * 16 * DD);
        const bfrag8 vf_2 = *(const bfrag8*)(vbase + (size_t)(tt + 2) * 512);

        const f32x4 reB0 = __builtin_amdgcn_mfma_f32_16x16x32_bf16(kf_n, qf0,  zero, 0, 0, 0);
        const f32x4 imB0 = __builtin_amdgcn_mfma_f32_16x16x32_bf16(kf_n, qpf0, zero, 0, 0, 0);
        const f32x4 reB1 = __builtin_amdgcn_mfma_f32_16x16x32_bf16(kf_n, qf1,  zero, 0, 0, 0);
        const f32x4 imB1 = __builtin_amdgcn_mfma_f32_16x16x32_bf16(kf_n, qpf1, zero, 0, 0, 0);

        const bfrag4 pf0 = expchain(reA0, imA0, SC2);
        const bfrag4 pf1 = expchain(reA1, imA1, SC2);

        union { bfrag8 v8; bfrag4 v4[2]; } vs; vs.v8 = vf_c;
        o00 = mfma16(pf0, vs.v4[0], o00);
        o01 = mfma16(pf0, vs.v4[1], o01);
        od0 = mfma16(pf0, ones,     od0);
        o10 = mfma16(pf1, vs.v4[0], o10);
        o11 = mfma16(pf1, vs.v4[1], o11);
        od1 = mfma16(pf1, ones,     od1);

        reA0 = reB0; imA0 = imB0; reA1 = reB1; imA1 = imB1;
        kf_n = kf_2; vf_c = vf_n; vf_n = vf_2;
    }

    __shared__ float cO[4][32][33];
    __shared__ float cD[4][32];
#pragma unroll
    for (int r = 0; r < 4; ++r) {
        cO[wave][4 * g + r][c]           = o00[r];
        cO[wave][4 * g + r][16 + c]      = o01[r];
        cO[wave][16 + 4 * g + r][c]      = o10[r];
        cO[wave][16 + 4 * g + r][16 + c] = o11[r];
    }
    if (c == 0) {
#pragma unroll
        for (int r = 0; r < 4; ++r) {
            cD[wave][4 * g + r]      = od0[r];
            cD[wave][16 + 4 * g + r] = od1[r];
        }
    }
    __syncthreads();

    const int q  = tid >> 3;
    const int dp = tid & 7;
    const float den  = (cD[0][q] + cD[1][q]) + (cD[2][q] + cD[3][q]);
    const float rden = 1.0f / den;
    float4 s;
    s.x = ((cO[0][q][4 * dp + 0] + cO[1][q][4 * dp + 0]) + (cO[2][q][4 * dp + 0] + cO[3][q][4 * dp + 0])) * rden;
    s.y = ((cO[0][q][4 * dp + 1] + cO[1][q][4 * dp + 1]) + (cO[2][q][4 * dp + 1] + cO[3][q][4 * dp + 1])) * rden;
    s.z = ((cO[0][q][4 * dp + 2] + cO[1][q][4 * dp + 2]) + (cO[2][q][4 * dp + 2] + cO[3][q][4 * dp + 2])) * rden;
    s.w = ((cO[0][q][4 * dp + 3] + cO[1][q][4 * dp + 3]) + (cO[2][q][4 * dp + 3] + cO[3][q][4 * dp + 3])) * rden;
    *(float4*)(outp + (size_t)(b * NN + qt * 32 + q) * DD + h * 32 + 4 * dp) = s;
}

// ---------------------------------------------------------------------------
// K3: gate MLP + in-place scale.  (r6-verified, unchanged)
// ---------------------------------------------------------------------------
__global__ __launch_bounds__(256) void gate_kernel(
    float* __restrict__ out,
    const float* __restrict__ Wg1, const float* __restrict__ Bg1,
    const float* __restrict__ Wg2, const float* __restrict__ Bg2)
{
    __shared__ float Ws[64][257];
    const int tid = threadIdx.x;
#pragma unroll
    for (int pass = 0; pass < 16; ++pass) {
        const int i = pass * 256 + tid;          // float4 chunk id
        const int r = i >> 6, qd = i & 63;
        float4 w = *(const float4*)(Wg1 + r * DD + qd * 4);
        Ws[r][qd * 4 + 0] = w.x;
        Ws[r][qd * 4 + 1] = w.y;
        Ws[r][qd * 4 + 2] = w.z;
        Ws[r][qd * 4 + 3] = w.w;
    }
    __syncthreads();

    const int wave = tid >> 6, lane = tid & 63;
    const int row  = blockIdx.x * 4 + wave;      // 0..4095
    float* orow = out + (size_t)row * DD;

    float s0 = 0.f, s1 = 0.f, s2 = 0.f, s3 = 0.f;
#pragma unroll 8
    for (int q = 0; q < 64; ++q) {
        float4 o = *(const float4*)(orow + q * 4);
        s0 += o.x * Ws[lane][q * 4 + 0];
        s1 += o.y * Ws[lane][q * 4 + 1];
        s2 += o.z * Ws[lane][q * 4 + 2];
        s3 += o.w * Ws[lane][q * 4 + 3];
    }
    float s = (s0 + s1) + (s2 + s3) + Bg1[lane];
    float hh = s / (1.0f + __expf(-s));
    float t = hh * Wg2[lane];
#pragma unroll
    for (int off = 32; off >= 1; off >>= 1) t += __shfl_xor(t, off, 64);
    const float gsc = 1.0f / (1.0f + __expf(-(t + Bg2[0])));

    float4 o = *(const float4*)(orow + lane * 4);
    o.x *= gsc; o.y *= gsc; o.z *= gsc; o.w *= gsc;
    *(float4*)(orow + lane * 4) = o;
}

// ---------------------------------------------------------------------------
extern "C" void kernel_launch(void* const* d_in, const int* in_sizes, int n_in,
                              void* d_out, int out_size, void* d_ws, size_t ws_size,
                              hipStream_t stream) {
    (void)in_sizes; (void)n_in; (void)out_size; (void)ws_size;
    const float* x   = (const float*)d_in[0];
    const float* wq  = (const float*)d_in[1];
    const float* bq  = (const float*)d_in[2];
    const float* wk  = (const float*)d_in[3];
    const float* bk  = (const float*)d_in[4];
    const float* wv  = (const float*)d_in[5];
    const float* bv  = (const float*)d_in[6];
    const float* wg1 = (const float*)d_in[7];
    const float* bg1 = (const float*)d_in[8];
    const float* wg2 = (const float*)d_in[9];
    const float* bg2 = (const float*)d_in[10];
    float* out = (float*)d_out;

    const size_t NE = (size_t)BB * NN * DD;   // 1048576
    unsigned short* Qb  = (unsigned short*)d_ws;
    unsigned short* Kb  = Qb  + NE;
    unsigned short* Vb  = Kb  + NE;
    unsigned short* Xb  = Vb  + NE;
    unsigned short* Wqb = Xb  + NE;
    unsigned short* Wkb = Wqb + 65536;
    unsigned short* Wvb = Wkb + 65536;
    float*          Dsc = (float*)(Wvb + 65536);   // diagnostic scratch output

    cvt_inputs<<<608, 256, 0, stream>>>(x, wq, wk, wv, Xb, Wqb, Wkb, Wvb);
    qkv_mfma<<<dim3(64, 4, 3), 256, 0, stream>>>(Xb, Wqb, Wkb, Wvb, bq, bk, bv,
                                                 Qb, Kb, Vb);
    attn_mfma8<<<dim3(1024), 512, 0, stream>>>(Qb, Kb, Vb, Dsc);   // diagnostic A
    attn_mfma<<<dim3(1024), 256, 0, stream>>>(Qb, Kb, Vb, out);    // real output B
    gate_kernel<<<dim3(1024), 256, 0, stream>>>(out, wg1, bg1, wg2, bg2);
}

// Round 9
// 62.290 us; speedup vs baseline: 1.4117x; 1.4117x over previous
//
#include <hip/hip_runtime.h>
#include <hip/hip_bf16.h>
#include <math.h>

#define BB 2
#define NN 2048
#define DD 256
#define HH 8

typedef __attribute__((ext_vector_type(8))) short bfrag8;
typedef __attribute__((ext_vector_type(4))) short bfrag4;
typedef __attribute__((ext_vector_type(4))) float f32x4;
typedef __attribute__((ext_vector_type(4))) unsigned short us4;
typedef __attribute__((ext_vector_type(8))) short s8v;

__device__ __forceinline__ unsigned short bf16rn(float f) {
    union { float f; unsigned u; } un; un.f = f;
    unsigned r = un.u + 0x7FFFu + ((un.u >> 16) & 1u);
    return (unsigned short)(r >> 16);
}

__device__ __forceinline__ f32x4 mfma16(bfrag4 a, bfrag4 b, f32x4 c) {
#if __has_builtin(__builtin_amdgcn_mfma_f32_16x16x16_bf16)
    return __builtin_amdgcn_mfma_f32_16x16x16_bf16(a, b, c, 0, 0, 0);
#else
    return __builtin_amdgcn_mfma_f32_16x16x16bf16_1k(a, b, c, 0, 0, 0);
#endif
}

// pair swizzle for the imag dot: {q0,q1,...} -> {q1,-q0,q3,-q2,...}
__device__ __forceinline__ bfrag8 pairswz(bfrag8 q) {
    union { bfrag8 f; unsigned u[4]; } a, r;
    a.f = q;
#pragma unroll
    for (int i = 0; i < 4; ++i) {
        unsigned d = a.u[i];
        r.u[i] = ((d >> 16) | (d << 16)) ^ 0x80000000u;
    }
    return r.f;
}

// w-chain: y = SC2 * re/|z|;  P = exp(y) via cubic Taylor (|y|<=0.0884);
// pack 4 probs to bf16 pairs with v_cvt_pk_bf16_f32.   (r3/r6-verified)
__device__ __forceinline__ bfrag4 expchain(f32x4 re, f32x4 im, float SC2) {
    float p[4];
#pragma unroll
    for (int r = 0; r < 4; ++r) {
        const float rr = re[r], ii = im[r];
        const float r2 = fmaf(rr, rr, fmaf(ii, ii, 1e-30f));
        const float y  = SC2 * rr * __builtin_amdgcn_rsqf(r2);
        const float a  = fmaf(y, 0.16666667f, 0.5f);
        const float bq = fmaf(y, a, 1.0f);
        p[r] = fmaf(y, bq, 1.0f);
    }
    unsigned lo, hi;
    asm("v_cvt_pk_bf16_f32 %0, %1, %2" : "=v"(lo) : "v"(p[0]), "v"(p[1]));
    asm("v_cvt_pk_bf16_f32 %0, %1, %2" : "=v"(hi) : "v"(p[2]), "v"(p[3]));
    union { unsigned u[2]; bfrag4 f; } pu;
    pu.u[0] = lo; pu.u[1] = hi;
    return pu.f;
}

// ---------------------------------------------------------------------------
// K0: convert X and Wq/Wk/Wv f32 -> bf16.  (r6-verified, unchanged)
// ---------------------------------------------------------------------------
__global__ __launch_bounds__(256) void cvt_inputs(
    const float* __restrict__ X,
    const float* __restrict__ Wq, const float* __restrict__ Wk, const float* __restrict__ Wv,
    unsigned short* __restrict__ Xb,
    unsigned short* __restrict__ Wqb, unsigned short* __restrict__ Wkb, unsigned short* __restrict__ Wvb)
{
    const int i = blockIdx.x * 256 + threadIdx.x;
    const float* src; unsigned short* dst; size_t off;
    if (i < 131072)      { src = X;  dst = Xb;  off = (size_t)i * 8; }
    else if (i < 139264) { src = Wq; dst = Wqb; off = (size_t)(i - 131072) * 8; }
    else if (i < 147456) { src = Wk; dst = Wkb; off = (size_t)(i - 139264) * 8; }
    else                 { src = Wv; dst = Wvb; off = (size_t)(i - 147456) * 8; }
    float4 a = *(const float4*)(src + off);
    float4 b = *(const float4*)(src + off + 4);
    us4 lo = { bf16rn(a.x), bf16rn(a.y), bf16rn(a.z), bf16rn(a.w) };
    us4 hi = { bf16rn(b.x), bf16rn(b.y), bf16rn(b.z), bf16rn(b.w) };
    *(us4*)(dst + off)     = lo;
    *(us4*)(dst + off + 4) = hi;
}

// ---------------------------------------------------------------------------
// K1: MFMA QKV GEMM (64x64 tile, XOR-swizzled LDS).  (r6-verified, unchanged)
// ---------------------------------------------------------------------------
__global__ __launch_bounds__(256) void qkv_mfma(
    const unsigned short* __restrict__ Xb,
    const unsigned short* __restrict__ Wqb, const unsigned short* __restrict__ Wkb,
    const unsigned short* __restrict__ Wvb,
    const float* __restrict__ bq, const float* __restrict__ bk, const float* __restrict__ bv,
    unsigned short* __restrict__ Qb, unsigned short* __restrict__ Kb, unsigned short* __restrict__ Vb)
{
    const int tid  = threadIdx.x;
    const int z    = blockIdx.z;
    const unsigned short* Wm = (z == 0) ? Wqb : (z == 1) ? Wkb : Wvb;
    const float*          bm = (z == 0) ? bq  : (z == 1) ? bk  : bv;

    const int Mbase = blockIdx.x * 64;
    const int Nbase = blockIdx.y * 64;

    __shared__ unsigned short Xs[64 * 64];
    __shared__ unsigned short Ws[64 * 64];

    const int wave = tid >> 6, lane = tid & 63;
    const int c = lane & 15, g = lane >> 4;

    const int srow = tid >> 2;
    const int sq   = tid & 3;
    const int soff = ((srow * 128 + sq * 16) ^ ((srow & 7) << 4));
    const unsigned short* gx = Xb + (size_t)(Mbase + srow) * DD + sq * 8;
    const unsigned short* gw = Wm + (size_t)(Nbase + srow) * DD + sq * 8;

    const int xrow = 16 * wave + c;
    const int xoff = ((xrow * 128 + g * 16) ^ ((xrow & 7) << 4));
    int woff[4];
#pragma unroll
    for (int j = 0; j < 4; ++j) {
        const int wrow = 16 * j + c;
        woff[j] = ((wrow * 128 + g * 16) ^ ((wrow & 7) << 4));
    }

    f32x4 acc[4];
#pragma unroll
    for (int j = 0; j < 4; ++j) acc[j] = (f32x4){0.f, 0.f, 0.f, 0.f};

    for (int k0 = 0; k0 < DD; k0 += 32) {
        *(s8v*)((char*)Xs + soff) = *(const s8v*)(gx + k0);
        *(s8v*)((char*)Ws + soff) = *(const s8v*)(gw + k0);
        __syncthreads();
        const bfrag8 xf = *(const bfrag8*)((const char*)Xs + xoff);
#pragma unroll
        for (int j = 0; j < 4; ++j) {
            const bfrag8 wf = *(const bfrag8*)((const char*)Ws + woff[j]);
            acc[j] = __builtin_amdgcn_mfma_f32_16x16x32_bf16(wf, xf, acc[j], 0, 0, 0);
        }
        __syncthreads();
    }

    const int n = Mbase + xrow;
    const int bb = n >> 11, m = n & (NN - 1);
#pragma unroll
    for (int j = 0; j < 4; ++j) {
        const int col0 = Nbase + 16 * j + 4 * g;
        float4 bias = *(const float4*)(bm + col0);
        float v0 = acc[j][0] + bias.x;
        float v1 = acc[j][1] + bias.y;
        float v2 = acc[j][2] + bias.z;
        float v3 = acc[j][3] + bias.w;
        if (z == 2) {
            const int t = m >> 4, gg = (m >> 2) & 3, jj = m & 3;
            const int h2 = col0 >> 5, dt = (col0 >> 4) & 1, cc0 = col0 & 15;
            const size_t base = (size_t)(bb * 8 + h2) * 65536
                              + (size_t)t * 512 + (size_t)(dt * 4 + jj);
            Vb[base + (size_t)(16 * gg + cc0 + 0) * 8] = bf16rn(v0);
            Vb[base + (size_t)(16 * gg + cc0 + 1) * 8] = bf16rn(v1);
            Vb[base + (size_t)(16 * gg + cc0 + 2) * 8] = bf16rn(v2);
            Vb[base + (size_t)(16 * gg + cc0 + 3) * 8] = bf16rn(v3);
        } else {
            us4 pk = { bf16rn(v0), bf16rn(v1), bf16rn(v2), bf16rn(v3) };
            unsigned short* Ob = (z == 0) ? Qb : Kb;
            *(us4*)(Ob + (size_t)n * DD + col0) = pk;
        }
    }
}

// ---------------------------------------------------------------------------
// K2: MFMA phase attention — 8 waves/block (512 thr), 256 keys/wave, 16 iters,
// software-pipelined (load tt+2 | score-MFMA tt+1 | expchain+PV tt).
// r8-diagnostic-verified at ~26 µs; promoted to produce the real output.
// LDS 34.8 KB -> 4 blocks/CU = 32 waves/CU (full).  Tail overrun tiles 16/17
// read in-bounds ws garbage, computed-then-discarded (finite bf16).
// ---------------------------------------------------------------------------
__global__ __launch_bounds__(512) void attn_mfma(
    const unsigned short* __restrict__ Qb, const unsigned short* __restrict__ Kb,
    const unsigned short* __restrict__ Vb, float* __restrict__ outp)
{
    const int tid  = threadIdx.x;
    const int wave = tid >> 6, lane = tid & 63;
    const int g = lane >> 4, c = lane & 15;
    const int bid  = blockIdx.x;                    // 1024 = 8 * 128
    const int wgid = (bid & 7) * 128 + (bid >> 3);  // bijective XCD cluster
    const int bh = wgid >> 6, qt = wgid & 63;
    const int b = bh >> 3, h = bh & 7;

    const size_t qoff = (size_t)(b * NN + qt * 32 + c) * DD + h * 32 + 8 * g;
    const bfrag8 qf0  = *(const bfrag8*)(Qb + qoff);
    const bfrag8 qf1  = *(const bfrag8*)(Qb + qoff + 16 * DD);
    const bfrag8 qpf0 = pairswz(qf0);
    const bfrag8 qpf1 = pairswz(qf1);

    const unsigned short* kbase = Kb + (size_t)(b * NN + wave * 256 + c) * DD + h * 32 + 8 * g;
    const unsigned short* vbase = Vb + (size_t)bh * 65536 + (size_t)(wave * 16) * 512 + lane * 8;

    const f32x4 zero = {0.f, 0.f, 0.f, 0.f};
    f32x4 o00 = zero, o01 = zero, od0 = zero;
    f32x4 o10 = zero, o11 = zero, od1 = zero;
    const bfrag4 ones = { 0x3F80, 0x3F80, 0x3F80, 0x3F80 };
    const float SC2 = 0.5f / (sqrtf(32.0f) + 1e-6f);

    // pipeline prologue: tile 0 score-MFMAs; tile 1 fragments in flight
    bfrag8 kf_n = *(const bfrag8*)(kbase + (size_t)16 * DD);
    bfrag8 vf_c = *(const bfrag8*)vbase;
    bfrag8 vf_n = *(const bfrag8*)(vbase + 512);

    f32x4 reA0, imA0, reA1, imA1;
    {
        const bfrag8 kf_c = *(const bfrag8*)kbase;
        reA0 = __builtin_amdgcn_mfma_f32_16x16x32_bf16(kf_c, qf0,  zero, 0, 0, 0);
        imA0 = __builtin_amdgcn_mfma_f32_16x16x32_bf16(kf_c, qpf0, zero, 0, 0, 0);
        reA1 = __builtin_amdgcn_mfma_f32_16x16x32_bf16(kf_c, qf1,  zero, 0, 0, 0);
        imA1 = __builtin_amdgcn_mfma_f32_16x16x32_bf16(kf_c, qpf1, zero, 0, 0, 0);
    }

#pragma unroll 2
    for (int tt = 0; tt < 16; ++tt) {
        const bfrag8 kf_2 = *(const bfrag8*)(kbase + (size_t)(tt + 2) * 16 * DD);
        const bfrag8 vf_2 = *(const bfrag8*)(vbase + (size_t)(tt + 2) * 512);

        const f32x4 reB0 = __builtin_amdgcn_mfma_f32_16x16x32_bf16(kf_n, qf0,  zero, 0, 0, 0);
        const f32x4 imB0 = __builtin_amdgcn_mfma_f32_16x16x32_bf16(kf_n, qpf0, zero, 0, 0, 0);
        const f32x4 reB1 = __builtin_amdgcn_mfma_f32_16x16x32_bf16(kf_n, qf1,  zero, 0, 0, 0);
        const f32x4 imB1 = __builtin_amdgcn_mfma_f32_16x16x32_bf16(kf_n, qpf1, zero, 0, 0, 0);

        const bfrag4 pf0 = expchain(reA0, imA0, SC2);
        const bfrag4 pf1 = expchain(reA1, imA1, SC2);

        union { bfrag8 v8; bfrag4 v4[2]; } vs; vs.v8 = vf_c;
        o00 = mfma16(pf0, vs.v4[0], o00);
        o01 = mfma16(pf0, vs.v4[1], o01);
        od0 = mfma16(pf0, ones,     od0);
        o10 = mfma16(pf1, vs.v4[0], o10);
        o11 = mfma16(pf1, vs.v4[1], o11);
        od1 = mfma16(pf1, ones,     od1);

        reA0 = reB0; imA0 = imB0; reA1 = reB1; imA1 = imB1;
        kf_n = kf_2; vf_c = vf_n; vf_n = vf_2;
    }

    __shared__ float cO[8][32][33];
    __shared__ float cD[8][32];
#pragma unroll
    for (int r = 0; r < 4; ++r) {
        cO[wave][4 * g + r][c]           = o00[r];
        cO[wave][4 * g + r][16 + c]      = o01[r];
        cO[wave][16 + 4 * g + r][c]      = o10[r];
        cO[wave][16 + 4 * g + r][16 + c] = o11[r];
    }
    if (c == 0) {
#pragma unroll
        for (int r = 0; r < 4; ++r) {
            cD[wave][4 * g + r]      = od0[r];
            cD[wave][16 + 4 * g + r] = od1[r];
        }
    }
    __syncthreads();

    const int q  = tid >> 4;   // 0..31
    const int dp = tid & 15;   // cols 2dp, 2dp+1
    float den = 0.f, s0 = 0.f, s1 = 0.f;
#pragma unroll
    for (int w = 0; w < 8; ++w) {
        den += cD[w][q];
        s0  += cO[w][q][2 * dp];
        s1  += cO[w][q][2 * dp + 1];
    }
    const float rden = 1.0f / den;
    float2 ov = make_float2(s0 * rden, s1 * rden);
    *(float2*)(outp + (size_t)(b * NN + qt * 32 + q) * DD + h * 32 + 2 * dp) = ov;
}

// ---------------------------------------------------------------------------
// K3: gate MLP + in-place scale.  (r6-verified, unchanged)
// ---------------------------------------------------------------------------
__global__ __launch_bounds__(256) void gate_kernel(
    float* __restrict__ out,
    const float* __restrict__ Wg1, const float* __restrict__ Bg1,
    const float* __restrict__ Wg2, const float* __restrict__ Bg2)
{
    __shared__ float Ws[64][257];
    const int tid = threadIdx.x;
#pragma unroll
    for (int pass = 0; pass < 16; ++pass) {
        const int i = pass * 256 + tid;          // float4 chunk id
        const int r = i >> 6, qd = i & 63;
        float4 w = *(const float4*)(Wg1 + r * DD + qd * 4);
        Ws[r][qd * 4 + 0] = w.x;
        Ws[r][qd * 4 + 1] = w.y;
        Ws[r][qd * 4 + 2] = w.z;
        Ws[r][qd * 4 + 3] = w.w;
    }
    __syncthreads();

    const int wave = tid >> 6, lane = tid & 63;
    const int row  = blockIdx.x * 4 + wave;      // 0..4095
    float* orow = out + (size_t)row * DD;

    float s0 = 0.f, s1 = 0.f, s2 = 0.f, s3 = 0.f;
#pragma unroll 8
    for (int q = 0; q < 64; ++q) {
        float4 o = *(const float4*)(orow + q * 4);
        s0 += o.x * Ws[lane][q * 4 + 0];
        s1 += o.y * Ws[lane][q * 4 + 1];
        s2 += o.z * Ws[lane][q * 4 + 2];
        s3 += o.w * Ws[lane][q * 4 + 3];
    }
    float s = (s0 + s1) + (s2 + s3) + Bg1[lane];
    float hh = s / (1.0f + __expf(-s));
    float t = hh * Wg2[lane];
#pragma unroll
    for (int off = 32; off >= 1; off >>= 1) t += __shfl_xor(t, off, 64);
    const float gsc = 1.0f / (1.0f + __expf(-(t + Bg2[0])));

    float4 o = *(const float4*)(orow + lane * 4);
    o.x *= gsc; o.y *= gsc; o.z *= gsc; o.w *= gsc;
    *(float4*)(orow + lane * 4) = o;
}

// ---------------------------------------------------------------------------
extern "C" void kernel_launch(void* const* d_in, const int* in_sizes, int n_in,
                              void* d_out, int out_size, void* d_ws, size_t ws_size,
                              hipStream_t stream) {
    (void)in_sizes; (void)n_in; (void)out_size; (void)ws_size;
    const float* x   = (const float*)d_in[0];
    const float* wq  = (const float*)d_in[1];
    const float* bq  = (const float*)d_in[2];
    const float* wk  = (const float*)d_in[3];
    const float* bk  = (const float*)d_in[4];
    const float* wv  = (const float*)d_in[5];
    const float* bv  = (const float*)d_in[6];
    const float* wg1 = (const float*)d_in[7];
    const float* bg1 = (const float*)d_in[8];
    const float* wg2 = (const float*)d_in[9];
    const float* bg2 = (const float*)d_in[10];
    float* out = (float*)d_out;

    const size_t NE = (size_t)BB * NN * DD;   // 1048576
    unsigned short* Qb  = (unsigned short*)d_ws;
    unsigned short* Kb  = Qb  + NE;
    unsigned short* Vb  = Kb  + NE;
    unsigned short* Xb  = Vb  + NE;
    unsigned short* Wqb = Xb  + NE;
    unsigned short* Wkb = Wqb + 65536;
    unsigned short* Wvb = Wkb + 65536;

    cvt_inputs<<<608, 256, 0, stream>>>(x, wq, wk, wv, Xb, Wqb, Wkb, Wvb);
    qkv_mfma<<<dim3(64, 4, 3), 256, 0, stream>>>(Xb, Wqb, Wkb, Wvb, bq, bk, bv,
                                                 Qb, Kb, Vb);
    attn_mfma<<<dim3(1024), 512, 0, stream>>>(Qb, Kb, Vb, out);
    gate_kernel<<<dim3(1024), 256, 0, stream>>>(out, wg1, bg1, wg2, bg2);
}